// Round 1
// baseline (246.699 us; speedup 1.0000x reference)
//
#include <hip/hip_runtime.h>
#include <hip/hip_bf16.h>

// Problem constants (B=1 folded out)
constexpr int T = 8;     // frames
constexpr int C = 128;   // input channels
constexpr int N = 4096;  // H*W positions
constexpr int F = 64;    // feature dim

typedef __bf16 bf16x8 __attribute__((ext_vector_type(8)));
typedef float  f32x4  __attribute__((ext_vector_type(4)));

// ---------------------------------------------------------------------------
// Kernel 1: projections Q = x1ᵀW1ᵀ+b1, K = x2ᵀW2ᵀ+b2, G = x1ᵀW3ᵀ+b3
// Output bf16 [t][n][F] in workspace.
// Block: 256 thr = 4 waves; each block does 64 n-positions of one t.
// ---------------------------------------------------------------------------
__global__ __launch_bounds__(256) void proj_kernel(
    const float* __restrict__ x1, const float* __restrict__ x2,
    const float* __restrict__ W1, const float* __restrict__ b1,
    const float* __restrict__ W2, const float* __restrict__ b2,
    const float* __restrict__ W3, const float* __restrict__ b3,
    __bf16* __restrict__ Qb, __bf16* __restrict__ Kb, __bf16* __restrict__ Gb)
{
    const int t  = blockIdx.x >> 6;   // 64 blocks per t
    const int nb = blockIdx.x & 63;
    const int n0 = nb * 64;

    constexpr int XS = C + 8;         // 136 bf16 stride -> 272B rows (16B aligned)
    __shared__ __bf16 Xt1[64 * XS];   // X1ᵀ tile: [n_local][c]
    __shared__ __bf16 Xt2[64 * XS];

    const int tid = threadIdx.x;
    // stage transposed (global read coalesced over n)
#pragma unroll
    for (int rep = 0; rep < 32; ++rep) {
        int idx = rep * 256 + tid;
        int c = idx >> 6, nl = idx & 63;
        size_t goff = ((size_t)t * C + c) * (size_t)N + n0 + nl;
        Xt1[nl * XS + c] = (__bf16)x1[goff];
        Xt2[nl * XS + c] = (__bf16)x2[goff];
    }
    __syncthreads();

    const int wave = tid >> 6, lane = tid & 63;
    const int quad = lane >> 4, l16 = lane & 15;

    // A-frags: A[m = n_local][k = c], lane m = l16, k = cc*32 + quad*8 + j
    bf16x8 a1[4], a2[4];
#pragma unroll
    for (int cc = 0; cc < 4; ++cc) {
        a1[cc] = *(const bf16x8*)&Xt1[(wave * 16 + l16) * XS + cc * 32 + quad * 8];
        a2[cc] = *(const bf16x8*)&Xt2[(wave * 16 + l16) * XS + cc * 32 + quad * 8];
    }

    const float* Ws[3]  = {W1, W2, W3};
    const float* bs[3]  = {b1, b2, b3};
    __bf16*      Os[3]  = {Qb, Kb, Gb};

#pragma unroll
    for (int p = 0; p < 3; ++p) {
        const float* W    = Ws[p];
        const float* bias = bs[p];
        __bf16*      O    = Os[p];

        f32x4 acc[4];
#pragma unroll
        for (int ft = 0; ft < 4; ++ft) acc[ft] = (f32x4){0.f, 0.f, 0.f, 0.f};

#pragma unroll
        for (int cc = 0; cc < 4; ++cc) {
#pragma unroll
            for (int ft = 0; ft < 4; ++ft) {
                // B[k = c][n = f]: lane n = ft*16+l16, k = cc*32+quad*8+j -> W[f][c]
                const float* wp = &W[(ft * 16 + l16) * C + cc * 32 + quad * 8];
                bf16x8 b;
#pragma unroll
                for (int j = 0; j < 8; ++j) b[j] = (__bf16)wp[j];
                bf16x8 a = (p == 1) ? a2[cc] : a1[cc];
                acc[ft] = __builtin_amdgcn_mfma_f32_16x16x32_bf16(a, b, acc[ft], 0, 0, 0);
            }
        }
        // C/D layout: col = l16 (f within subtile), row = quad*4 + r (n within 16)
#pragma unroll
        for (int ft = 0; ft < 4; ++ft) {
            int f = ft * 16 + l16;
            float bv = bias[f];
#pragma unroll
            for (int r = 0; r < 4; ++r) {
                int n = n0 + wave * 16 + quad * 4 + r;
                O[((size_t)t * N + n) * F + f] = (__bf16)(acc[ft][r] + bv);
            }
        }
    }
}

// ---------------------------------------------------------------------------
// Kernel 2: O[t][q][f] = sum_key relu(Q[q]·K[key]) * G[key][f], streamed over
// 64-key tiles (flash-style, no softmax so no rescaling).
// Block: 256 thr = 4 waves; BM = 64 queries per block (wave owns 16 rows).
// Output written as fp32 [t][f][n] (== reference permute).
// ---------------------------------------------------------------------------
__global__ __launch_bounds__(256) void attn_kernel(
    const __bf16* __restrict__ Qb, const __bf16* __restrict__ Kb,
    const __bf16* __restrict__ Gb, float* __restrict__ out)
{
    const int t  = blockIdx.x >> 6;
    const int qb = blockIdx.x & 63;
    const int q0 = qb * 64;

    constexpr int KS = 72;            // bf16 stride (144B rows, 16B aligned)
    __shared__ __bf16 Kt[64 * KS];    // K tile [key][f]
    __shared__ __bf16 Gt[64 * KS];    // G tile transposed [f][key]
    __shared__ float  Sf[64 * KS];    // S tile (bf16 view) in loop; O (f32) at epilogue
    __bf16* Sb = (__bf16*)Sf;

    const int tid = threadIdx.x, wave = tid >> 6, lane = tid & 63;
    const int quad = lane >> 4, l16 = lane & 15;

    // Q A-frags for this wave's 16 query rows: A[m=q][k=f]
    bf16x8 qf[2];
    {
        const __bf16* qrow = &Qb[((size_t)t * N + q0 + wave * 16 + l16) * F];
        qf[0] = *(const bf16x8*)&qrow[quad * 8];
        qf[1] = *(const bf16x8*)&qrow[32 + quad * 8];
    }

    f32x4 oacc[4];
#pragma unroll
    for (int ft = 0; ft < 4; ++ft) oacc[ft] = (f32x4){0.f, 0.f, 0.f, 0.f};

    for (int kb = 0; kb < N / 64; ++kb) {
        const int k0 = kb * 64;
        __syncthreads();   // previous iteration's Kt/Gt reads must finish
        // stage K and transposed G: 64x64 bf16 each; 512 x 8-elem units
#pragma unroll
        for (int rep = 0; rep < 2; ++rep) {
            int u  = rep * 256 + tid;       // 0..511
            int kr = u >> 3, fc = (u & 7) * 8;
            size_t gbase = ((size_t)t * N + k0 + kr) * F + fc;
            *(bf16x8*)&Kt[kr * KS + fc] = *(const bf16x8*)&Kb[gbase];
            bf16x8 g = *(const bf16x8*)&Gb[gbase];
#pragma unroll
            for (int j = 0; j < 8; ++j) Gt[(fc + j) * KS + kr] = g[j];
        }
        __syncthreads();

        // S = relu(Q·Kᵀ) for this wave's 16 rows x 64 keys, write bf16 to Sb
#pragma unroll
        for (int nt = 0; nt < 4; ++nt) {
            f32x4 s = (f32x4){0.f, 0.f, 0.f, 0.f};
            bf16x8 b0 = *(const bf16x8*)&Kt[(nt * 16 + l16) * KS + quad * 8];
            bf16x8 b1 = *(const bf16x8*)&Kt[(nt * 16 + l16) * KS + 32 + quad * 8];
            s = __builtin_amdgcn_mfma_f32_16x16x32_bf16(qf[0], b0, s, 0, 0, 0);
            s = __builtin_amdgcn_mfma_f32_16x16x32_bf16(qf[1], b1, s, 0, 0, 0);
#pragma unroll
            for (int r = 0; r < 4; ++r) {
                float v = fmaxf(s[r], 0.f);
                Sb[(wave * 16 + quad * 4 + r) * KS + nt * 16 + l16] = (__bf16)v;
            }
        }
        // PV: wave reads back only its OWN 16 Sb rows -> no __syncthreads needed
        bf16x8 s0 = *(const bf16x8*)&Sb[(wave * 16 + l16) * KS + quad * 8];
        bf16x8 s1 = *(const bf16x8*)&Sb[(wave * 16 + l16) * KS + 32 + quad * 8];
#pragma unroll
        for (int ft = 0; ft < 4; ++ft) {
            bf16x8 g0 = *(const bf16x8*)&Gt[(ft * 16 + l16) * KS + quad * 8];
            bf16x8 g1 = *(const bf16x8*)&Gt[(ft * 16 + l16) * KS + 32 + quad * 8];
            oacc[ft] = __builtin_amdgcn_mfma_f32_16x16x32_bf16(s0, g0, oacc[ft], 0, 0, 0);
            oacc[ft] = __builtin_amdgcn_mfma_f32_16x16x32_bf16(s1, g1, oacc[ft], 0, 0, 0);
        }
    }

    // Epilogue: transpose O through LDS for coalesced [t][f][n] stores
    __syncthreads();
#pragma unroll
    for (int ft = 0; ft < 4; ++ft) {
        int f = ft * 16 + l16;
#pragma unroll
        for (int r = 0; r < 4; ++r) {
            int nl = wave * 16 + quad * 4 + r;
            Sf[f * KS + nl] = oacc[ft][r];
        }
    }
    __syncthreads();
#pragma unroll
    for (int rep = 0; rep < 16; ++rep) {
        int idx = rep * 256 + tid;        // 0..4095
        int f = idx >> 6, nl = idx & 63;
        out[((size_t)t * F + f) * (size_t)N + q0 + nl] = Sf[f * KS + nl];
    }
}

// ---------------------------------------------------------------------------
extern "C" void kernel_launch(void* const* d_in, const int* in_sizes, int n_in,
                              void* d_out, int out_size, void* d_ws, size_t ws_size,
                              hipStream_t stream) {
    const float* x1 = (const float*)d_in[0];
    const float* x2 = (const float*)d_in[1];
    const float* W1 = (const float*)d_in[2];
    const float* b1 = (const float*)d_in[3];
    const float* W2 = (const float*)d_in[4];
    const float* b2 = (const float*)d_in[5];
    const float* W3 = (const float*)d_in[6];
    const float* b3 = (const float*)d_in[7];
    float* out = (float*)d_out;

    // workspace: Q, K, G as bf16 [T][N][F]  (3 * 4 MiB = 12 MiB)
    __bf16* Qb = (__bf16*)d_ws;
    __bf16* Kb = Qb + (size_t)T * N * F;
    __bf16* Gb = Kb + (size_t)T * N * F;

    proj_kernel<<<dim3(T * (N / 64)), dim3(256), 0, stream>>>(
        x1, x2, W1, b1, W2, b2, W3, b3, Qb, Kb, Gb);
    attn_kernel<<<dim3(T * (N / 64)), dim3(256), 0, stream>>>(Qb, Kb, Gb, out);
}

// Round 2
// 179.504 us; speedup vs baseline: 1.3743x; 1.3743x over previous
//
#include <hip/hip_runtime.h>
#include <hip/hip_bf16.h>

// Problem constants (B=1 folded out)
constexpr int T = 8;     // frames
constexpr int C = 128;   // input channels
constexpr int N = 4096;  // H*W positions
constexpr int F = 64;    // feature dim

typedef __bf16 bf16x8 __attribute__((ext_vector_type(8)));
typedef float  f32x4  __attribute__((ext_vector_type(4)));

// ---------------------------------------------------------------------------
// Kernel 0: convert W1/W2/W3 (fp32 [F][C]) to bf16, packed [3][F][C]
// ---------------------------------------------------------------------------
__global__ __launch_bounds__(256) void prep_w_kernel(
    const float* __restrict__ W1, const float* __restrict__ W2,
    const float* __restrict__ W3, __bf16* __restrict__ Wb)
{
    int i = blockIdx.x * 256 + threadIdx.x;   // grid covers 3*F*C = 24576
    const float* Ws[3] = {W1, W2, W3};
    int p = i >> 13, r = i & 8191;
    Wb[i] = (__bf16)Ws[p][r];
}

// ---------------------------------------------------------------------------
// Kernel 0b: zero d_out (it is poisoned 0xAA before every launch; attn
// accumulates into it with atomics)
// ---------------------------------------------------------------------------
__global__ __launch_bounds__(256) void zero_out_kernel(float* __restrict__ out)
{
    int i = blockIdx.x * 256 + threadIdx.x;   // grid covers T*F*N/4 float4s
    ((f32x4*)out)[i] = (f32x4){0.f, 0.f, 0.f, 0.f};
}

// ---------------------------------------------------------------------------
// Kernel 1: projections.
//   Q = x1ᵀW1ᵀ+b1  -> bf16 [t][n][F]
//   K = x2ᵀW2ᵀ+b2  -> bf16 [t][n][F]
//   G = x1ᵀW3ᵀ+b3  -> bf16 [t][f][N]  (TRANSPOSED, so attn can stage it
//                                       conflict-free with vector writes)
// Block: 256 thr = 4 waves; 64 n-positions of one t per block.
// ---------------------------------------------------------------------------
__global__ __launch_bounds__(256) void proj_kernel(
    const float* __restrict__ x1, const float* __restrict__ x2,
    const __bf16* __restrict__ Wb,
    const float* __restrict__ b1, const float* __restrict__ b2,
    const float* __restrict__ b3,
    __bf16* __restrict__ Qb, __bf16* __restrict__ Kb, __bf16* __restrict__ Gw)
{
    const int t  = blockIdx.x >> 6;
    const int nb = blockIdx.x & 63;
    const int n0 = nb * 64;

    constexpr int XS = C + 8;         // 136 bf16 -> 272B rows (16B aligned)
    __shared__ __bf16 Xt1[64 * XS];   // X1ᵀ tile: [n_local][c]
    __shared__ __bf16 Xt2[64 * XS];

    const int tid = threadIdx.x;
#pragma unroll
    for (int rep = 0; rep < 32; ++rep) {
        int idx = rep * 256 + tid;
        int c = idx >> 6, nl = idx & 63;
        size_t goff = ((size_t)t * C + c) * (size_t)N + n0 + nl;
        Xt1[nl * XS + c] = (__bf16)x1[goff];
        Xt2[nl * XS + c] = (__bf16)x2[goff];
    }
    __syncthreads();

    const int wave = tid >> 6, lane = tid & 63;
    const int quad = lane >> 4, l16 = lane & 15;

    // A-frags for Q/K: A[m = n_local][k = c]
    bf16x8 a1[4], a2[4];
#pragma unroll
    for (int cc = 0; cc < 4; ++cc) {
        a1[cc] = *(const bf16x8*)&Xt1[(wave * 16 + l16) * XS + cc * 32 + quad * 8];
        a2[cc] = *(const bf16x8*)&Xt2[(wave * 16 + l16) * XS + cc * 32 + quad * 8];
    }

    // ---- Q and K: D[m=n][n'=f], wave owns 16 n-rows ----
#pragma unroll
    for (int p = 0; p < 2; ++p) {
        const __bf16* W    = Wb + (size_t)p * F * C;
        const float*  bias = p ? b2 : b1;
        __bf16*       O    = p ? Kb : Qb;

        f32x4 acc[4];
#pragma unroll
        for (int ft = 0; ft < 4; ++ft) acc[ft] = (f32x4){0.f, 0.f, 0.f, 0.f};
#pragma unroll
        for (int cc = 0; cc < 4; ++cc) {
#pragma unroll
            for (int ft = 0; ft < 4; ++ft) {
                // B[k=c][n'=f] = W[f][c], f = ft*16+l16, c = cc*32+quad*8+j
                bf16x8 b = *(const bf16x8*)&W[(ft * 16 + l16) * C + cc * 32 + quad * 8];
                bf16x8 a = p ? a2[cc] : a1[cc];
                acc[ft] = __builtin_amdgcn_mfma_f32_16x16x32_bf16(a, b, acc[ft], 0, 0, 0);
            }
        }
#pragma unroll
        for (int ft = 0; ft < 4; ++ft) {
            int f = ft * 16 + l16;
            float bv = bias[f];
#pragma unroll
            for (int r = 0; r < 4; ++r) {
                int n = n0 + wave * 16 + quad * 4 + r;
                O[((size_t)t * N + n) * F + f] = (__bf16)(acc[ft][r] + bv);
            }
        }
    }

    // ---- G transposed: D[m=f][n'=npos], wave owns 16 f-rows (wave = ft) ----
    {
        const __bf16* W3b = Wb + (size_t)2 * F * C;
        // A[m=f][k=c] = W3[f][c], f = wave*16+l16
        bf16x8 wa[4];
#pragma unroll
        for (int cc = 0; cc < 4; ++cc)
            wa[cc] = *(const bf16x8*)&W3b[(wave * 16 + l16) * C + cc * 32 + quad * 8];

        f32x4 acc[4];
#pragma unroll
        for (int nt = 0; nt < 4; ++nt) acc[nt] = (f32x4){0.f, 0.f, 0.f, 0.f};
#pragma unroll
        for (int cc = 0; cc < 4; ++cc) {
#pragma unroll
            for (int nt = 0; nt < 4; ++nt) {
                // B[k=c][n'=npos] = x1ᵀ[npos][c], npos = nt*16+l16
                bf16x8 b = *(const bf16x8*)&Xt1[(nt * 16 + l16) * XS + cc * 32 + quad * 8];
                acc[nt] = __builtin_amdgcn_mfma_f32_16x16x32_bf16(wa[cc], b, acc[nt], 0, 0, 0);
            }
        }
#pragma unroll
        for (int nt = 0; nt < 4; ++nt) {
#pragma unroll
            for (int r = 0; r < 4; ++r) {
                int f = wave * 16 + quad * 4 + r;     // D row -> f
                int n = n0 + nt * 16 + l16;           // D col -> npos
                Gw[((size_t)t * F + f) * (size_t)N + n] = (__bf16)(acc[nt][r] + b3[f]);
            }
        }
    }
}

// ---------------------------------------------------------------------------
// Kernel 2: O[t][f][q] += sum_key relu(Q[q]·K[key]) * G[key][f]
// Grid: T * 64 q-blocks * KSPLIT key-splits. Block 256 = 4 waves, BM=64.
// PV computed as Oᵀ = Gᵀ·Sᵀ (swapped MFMA operands) so the C-layout IS the
// output layout — no epilogue transpose. fp32 atomic accumulate over splits.
// ---------------------------------------------------------------------------
constexpr int KSPLIT = 2;

__global__ __launch_bounds__(256) void attn_kernel(
    const __bf16* __restrict__ Qb, const __bf16* __restrict__ Kb,
    const __bf16* __restrict__ Gw, float* __restrict__ out)
{
    const int ks = blockIdx.x & (KSPLIT - 1);
    const int qb = (blockIdx.x >> 1) & 63;
    const int t  = blockIdx.x >> 7;
    const int q0 = qb * 64;

    constexpr int KS = 72;            // bf16 stride (144B rows, 16B aligned)
    __shared__ __bf16 Kt[64 * KS];    // K tile [key][f]
    __shared__ __bf16 Gt[64 * KS];    // G tile [f][key] (already transposed in global)
    __shared__ __bf16 Sb[64 * KS];    // S tile [q][key] bf16

    const int tid = threadIdx.x, wave = tid >> 6, lane = tid & 63;
    const int quad = lane >> 4, l16 = lane & 15;

    // Q A-frags for this wave's 16 query rows: A[m=q][k=f]
    bf16x8 qf[2];
    {
        const __bf16* qrow = &Qb[((size_t)t * N + q0 + wave * 16 + l16) * F];
        qf[0] = *(const bf16x8*)&qrow[quad * 8];
        qf[1] = *(const bf16x8*)&qrow[32 + quad * 8];
    }

    f32x4 oacc[4];
#pragma unroll
    for (int ft = 0; ft < 4; ++ft) oacc[ft] = (f32x4){0.f, 0.f, 0.f, 0.f};

    const int kb_lo = ks * (N / 64 / KSPLIT);
    const int kb_hi = kb_lo + (N / 64 / KSPLIT);

    for (int kb = kb_lo; kb < kb_hi; ++kb) {
        const int k0 = kb * 64;
        __syncthreads();   // previous iteration's Kt/Gt reads must finish
        // stage K [key][f] and G [f][key]: 512 x 16B units each, all vector
        // writes, bank-balanced (dword-group stride 4 cycles all 8 groups)
#pragma unroll
        for (int rep = 0; rep < 2; ++rep) {
            int u  = rep * 256 + tid;       // 0..511
            int r8 = u >> 3, c8 = (u & 7) * 8;
            *(bf16x8*)&Kt[r8 * KS + c8] =
                *(const bf16x8*)&Kb[((size_t)t * N + k0 + r8) * F + c8];
            *(bf16x8*)&Gt[r8 * KS + c8] =
                *(const bf16x8*)&Gw[((size_t)t * F + r8) * (size_t)N + k0 + c8];
        }
        __syncthreads();

        // S = relu(Q·Kᵀ): wave's 16 q-rows x 64 keys -> bf16 Sb[q][key]
#pragma unroll
        for (int nt = 0; nt < 4; ++nt) {
            f32x4 s = (f32x4){0.f, 0.f, 0.f, 0.f};
            bf16x8 b0 = *(const bf16x8*)&Kt[(nt * 16 + l16) * KS + quad * 8];
            bf16x8 b1 = *(const bf16x8*)&Kt[(nt * 16 + l16) * KS + 32 + quad * 8];
            s = __builtin_amdgcn_mfma_f32_16x16x32_bf16(qf[0], b0, s, 0, 0, 0);
            s = __builtin_amdgcn_mfma_f32_16x16x32_bf16(qf[1], b1, s, 0, 0, 0);
#pragma unroll
            for (int r = 0; r < 4; ++r) {
                float v = fmaxf(s[r], 0.f);
                Sb[(wave * 16 + quad * 4 + r) * KS + nt * 16 + l16] = (__bf16)v;
            }
        }
        // PV as Oᵀ: D[m=f][n=q] = Σ_key Gt[f][key] * Sb[q][key]
        // (wave reads only its OWN 16 Sb rows -> no barrier needed)
        bf16x8 s0 = *(const bf16x8*)&Sb[(wave * 16 + l16) * KS + quad * 8];
        bf16x8 s1 = *(const bf16x8*)&Sb[(wave * 16 + l16) * KS + 32 + quad * 8];
#pragma unroll
        for (int ft = 0; ft < 4; ++ft) {
            bf16x8 g0 = *(const bf16x8*)&Gt[(ft * 16 + l16) * KS + quad * 8];
            bf16x8 g1 = *(const bf16x8*)&Gt[(ft * 16 + l16) * KS + 32 + quad * 8];
            oacc[ft] = __builtin_amdgcn_mfma_f32_16x16x32_bf16(g0, s0, oacc[ft], 0, 0, 0);
            oacc[ft] = __builtin_amdgcn_mfma_f32_16x16x32_bf16(g1, s1, oacc[ft], 0, 0, 0);
        }
    }

    // Epilogue: D row = f (quad*4+r within ft), col = q (l16). Direct atomic
    // accumulate into out[t][f][n] — no LDS transpose.
#pragma unroll
    for (int ft = 0; ft < 4; ++ft) {
#pragma unroll
        for (int r = 0; r < 4; ++r) {
            int f = ft * 16 + quad * 4 + r;
            int q = q0 + wave * 16 + l16;
            unsafeAtomicAdd(&out[((size_t)t * F + f) * (size_t)N + q], oacc[ft][r]);
        }
    }
}

// ---------------------------------------------------------------------------
extern "C" void kernel_launch(void* const* d_in, const int* in_sizes, int n_in,
                              void* d_out, int out_size, void* d_ws, size_t ws_size,
                              hipStream_t stream) {
    const float* x1 = (const float*)d_in[0];
    const float* x2 = (const float*)d_in[1];
    const float* W1 = (const float*)d_in[2];
    const float* b1 = (const float*)d_in[3];
    const float* W2 = (const float*)d_in[4];
    const float* b2 = (const float*)d_in[5];
    const float* W3 = (const float*)d_in[6];
    const float* b3 = (const float*)d_in[7];
    float* out = (float*)d_out;

    // workspace: Q [t][n][F], K [t][n][F], G [t][f][N] bf16 (3x4 MiB), Wb bf16
    __bf16* Qb = (__bf16*)d_ws;
    __bf16* Kb = Qb + (size_t)T * N * F;
    __bf16* Gw = Kb + (size_t)T * N * F;
    __bf16* Wb = Gw + (size_t)T * N * F;

    prep_w_kernel<<<dim3(3 * F * C / 256), dim3(256), 0, stream>>>(W1, W2, W3, Wb);
    proj_kernel<<<dim3(T * (N / 64)), dim3(256), 0, stream>>>(
        x1, x2, Wb, b1, b2, b3, Qb, Kb, Gw);
    zero_out_kernel<<<dim3(T * F * N / 4 / 256), dim3(256), 0, stream>>>(out);
    attn_kernel<<<dim3(T * (N / 64) * KSPLIT), dim3(256), 0, stream>>>(Qb, Kb, Gw, out);
}

// Round 3
// 162.311 us; speedup vs baseline: 1.5199x; 1.1059x over previous
//
#include <hip/hip_runtime.h>
#include <hip/hip_bf16.h>

// Problem constants (B=1 folded out)
constexpr int T = 8;     // frames
constexpr int C = 128;   // input channels
constexpr int N = 4096;  // H*W positions
constexpr int F = 64;    // feature dim

typedef __bf16 bf16x8 __attribute__((ext_vector_type(8)));
typedef __bf16 bf16x4 __attribute__((ext_vector_type(4)));
typedef float  f32x4  __attribute__((ext_vector_type(4)));

// ---------------------------------------------------------------------------
// Kernel 0: convert W1/W2/W3 (fp32 [F][C]) to bf16, packed [3][F][C]
// ---------------------------------------------------------------------------
__global__ __launch_bounds__(256) void prep_w_kernel(
    const float* __restrict__ W1, const float* __restrict__ W2,
    const float* __restrict__ W3, __bf16* __restrict__ Wb)
{
    int i = blockIdx.x * 256 + threadIdx.x;   // grid covers 3*F*C = 24576
    const float* Ws[3] = {W1, W2, W3};
    int p = i >> 13, r = i & 8191;
    Wb[i] = (__bf16)Ws[p][r];
}

// ---------------------------------------------------------------------------
// Kernel 0b: zero d_out (poisoned 0xAA before every launch; attn accumulates
// into it with atomics)
// ---------------------------------------------------------------------------
__global__ __launch_bounds__(256) void zero_out_kernel(float* __restrict__ out)
{
    int i = blockIdx.x * 256 + threadIdx.x;   // grid covers T*F*N/4 float4s
    ((f32x4*)out)[i] = (f32x4){0.f, 0.f, 0.f, 0.f};
}

// ---------------------------------------------------------------------------
// Kernel 1: projections (unchanged from R2 — re-measure with attn lowered).
//   Q = x1ᵀW1ᵀ+b1  -> bf16 [t][n][F]
//   K = x2ᵀW2ᵀ+b2  -> bf16 [t][n][F]
//   G = x1ᵀW3ᵀ+b3  -> bf16 [t][f][N]  (transposed for conflict-free attn staging)
// ---------------------------------------------------------------------------
__global__ __launch_bounds__(256) void proj_kernel(
    const float* __restrict__ x1, const float* __restrict__ x2,
    const __bf16* __restrict__ Wb,
    const float* __restrict__ b1, const float* __restrict__ b2,
    const float* __restrict__ b3,
    __bf16* __restrict__ Qb, __bf16* __restrict__ Kb, __bf16* __restrict__ Gw)
{
    const int t  = blockIdx.x >> 6;
    const int nb = blockIdx.x & 63;
    const int n0 = nb * 64;

    constexpr int XS = C + 8;         // 136 bf16 -> 272B rows (16B aligned)
    __shared__ __bf16 Xt1[64 * XS];   // X1ᵀ tile: [n_local][c]
    __shared__ __bf16 Xt2[64 * XS];

    const int tid = threadIdx.x;
#pragma unroll
    for (int rep = 0; rep < 32; ++rep) {
        int idx = rep * 256 + tid;
        int c = idx >> 6, nl = idx & 63;
        size_t goff = ((size_t)t * C + c) * (size_t)N + n0 + nl;
        Xt1[nl * XS + c] = (__bf16)x1[goff];
        Xt2[nl * XS + c] = (__bf16)x2[goff];
    }
    __syncthreads();

    const int wave = tid >> 6, lane = tid & 63;
    const int quad = lane >> 4, l16 = lane & 15;

    bf16x8 a1[4], a2[4];
#pragma unroll
    for (int cc = 0; cc < 4; ++cc) {
        a1[cc] = *(const bf16x8*)&Xt1[(wave * 16 + l16) * XS + cc * 32 + quad * 8];
        a2[cc] = *(const bf16x8*)&Xt2[(wave * 16 + l16) * XS + cc * 32 + quad * 8];
    }

    // ---- Q and K: D[m=n][n'=f] ----
#pragma unroll
    for (int p = 0; p < 2; ++p) {
        const __bf16* W    = Wb + (size_t)p * F * C;
        const float*  bias = p ? b2 : b1;
        __bf16*       O    = p ? Kb : Qb;

        f32x4 acc[4];
#pragma unroll
        for (int ft = 0; ft < 4; ++ft) acc[ft] = (f32x4){0.f, 0.f, 0.f, 0.f};
#pragma unroll
        for (int cc = 0; cc < 4; ++cc) {
#pragma unroll
            for (int ft = 0; ft < 4; ++ft) {
                bf16x8 b = *(const bf16x8*)&W[(ft * 16 + l16) * C + cc * 32 + quad * 8];
                bf16x8 a = p ? a2[cc] : a1[cc];
                acc[ft] = __builtin_amdgcn_mfma_f32_16x16x32_bf16(a, b, acc[ft], 0, 0, 0);
            }
        }
#pragma unroll
        for (int ft = 0; ft < 4; ++ft) {
            int f = ft * 16 + l16;
            float bv = bias[f];
#pragma unroll
            for (int r = 0; r < 4; ++r) {
                int n = n0 + wave * 16 + quad * 4 + r;
                O[((size_t)t * N + n) * F + f] = (__bf16)(acc[ft][r] + bv);
            }
        }
    }

    // ---- G transposed: D[m=f][n'=npos] ----
    {
        const __bf16* W3b = Wb + (size_t)2 * F * C;
        bf16x8 wa[4];
#pragma unroll
        for (int cc = 0; cc < 4; ++cc)
            wa[cc] = *(const bf16x8*)&W3b[(wave * 16 + l16) * C + cc * 32 + quad * 8];

        f32x4 acc[4];
#pragma unroll
        for (int nt = 0; nt < 4; ++nt) acc[nt] = (f32x4){0.f, 0.f, 0.f, 0.f};
#pragma unroll
        for (int cc = 0; cc < 4; ++cc) {
#pragma unroll
            for (int nt = 0; nt < 4; ++nt) {
                bf16x8 b = *(const bf16x8*)&Xt1[(nt * 16 + l16) * XS + cc * 32 + quad * 8];
                acc[nt] = __builtin_amdgcn_mfma_f32_16x16x32_bf16(wa[cc], b, acc[nt], 0, 0, 0);
            }
        }
#pragma unroll
        for (int nt = 0; nt < 4; ++nt) {
#pragma unroll
            for (int r = 0; r < 4; ++r) {
                int f = wave * 16 + quad * 4 + r;
                int n = n0 + nt * 16 + l16;
                Gw[((size_t)t * F + f) * (size_t)N + n] = (__bf16)(acc[nt][r] + b3[f]);
            }
        }
    }
}

// ---------------------------------------------------------------------------
// Kernel 2: O[t][f][q] += sum_key relu(Q[q]·K[key]) * G[key][f]
// Block 256 = 4 waves; BM = 128 (32 q-rows per wave, 2 q-groups of 16).
// S-GEMM computes Sᵀ (D[key][q]) so its C-layout packs 4 consecutive keys per
// lane -> b64 Sb writes. PV computes Oᵀ (D[f][q]) -> direct atomic epilogue.
// Next K/G tile register-prefetched during compute.
// ---------------------------------------------------------------------------
constexpr int KSPLIT = 2;

__global__ __launch_bounds__(256) void attn_kernel(
    const __bf16* __restrict__ Qb, const __bf16* __restrict__ Kb,
    const __bf16* __restrict__ Gw, float* __restrict__ out)
{
    const int ks = blockIdx.x & (KSPLIT - 1);
    const int qb = (blockIdx.x / KSPLIT) & 31;   // N/128 = 32 q-blocks
    const int t  = blockIdx.x / (KSPLIT * 32);
    const int q0 = qb * 128;

    constexpr int KS = 72;              // bf16 stride (144B rows)
    __shared__ __bf16 Kt[64 * KS];      // K tile [key][f]
    __shared__ __bf16 Gt[64 * KS];      // G tile [f][key]
    __shared__ __bf16 Sb[128 * KS];     // Sᵀ-written, read as S [q][key]

    const int tid = threadIdx.x, wave = tid >> 6, lane = tid & 63;
    const int quad = lane >> 4, l16 = lane & 15;

    // Q B-frags: B[n=q][k=f], q = q0 + wave*32 + qg*16 + l16
    bf16x8 qf[2][2];
#pragma unroll
    for (int qg = 0; qg < 2; ++qg) {
        const __bf16* qrow = &Qb[((size_t)t * N + q0 + wave * 32 + qg * 16 + l16) * F];
        qf[qg][0] = *(const bf16x8*)&qrow[quad * 8];
        qf[qg][1] = *(const bf16x8*)&qrow[32 + quad * 8];
    }

    f32x4 oacc[4][2];
#pragma unroll
    for (int ft = 0; ft < 4; ++ft)
#pragma unroll
        for (int qg = 0; qg < 2; ++qg) oacc[ft][qg] = (f32x4){0.f, 0.f, 0.f, 0.f};

    const int kb_lo = ks * (N / 64 / KSPLIT);
    const int kb_hi = kb_lo + (N / 64 / KSPLIT);

    // staging unit for this thread: u in {tid, tid+256}; r8 = u>>3, c8 = (u&7)*8
    const int r8a = tid >> 3,          c8a = (tid & 7) * 8;
    const int r8b = (tid + 256) >> 3,  c8b = c8a;

    // prefetch tile kb_lo into registers
    bf16x8 kv0, kv1, gv0, gv1;
    {
        const int k0 = kb_lo * 64;
        kv0 = *(const bf16x8*)&Kb[((size_t)t * N + k0 + r8a) * F + c8a];
        kv1 = *(const bf16x8*)&Kb[((size_t)t * N + k0 + r8b) * F + c8b];
        gv0 = *(const bf16x8*)&Gw[((size_t)t * F + r8a) * (size_t)N + k0 + c8a];
        gv1 = *(const bf16x8*)&Gw[((size_t)t * F + r8b) * (size_t)N + k0 + c8b];
    }

    for (int kb = kb_lo; kb < kb_hi; ++kb) {
        __syncthreads();   // previous tile's LDS reads done
        *(bf16x8*)&Kt[r8a * KS + c8a] = kv0;
        *(bf16x8*)&Kt[r8b * KS + c8b] = kv1;
        *(bf16x8*)&Gt[r8a * KS + c8a] = gv0;
        *(bf16x8*)&Gt[r8b * KS + c8b] = gv1;
        __syncthreads();

        if (kb + 1 < kb_hi) {   // prefetch next tile (overlaps with compute)
            const int k0 = (kb + 1) * 64;
            kv0 = *(const bf16x8*)&Kb[((size_t)t * N + k0 + r8a) * F + c8a];
            kv1 = *(const bf16x8*)&Kb[((size_t)t * N + k0 + r8b) * F + c8b];
            gv0 = *(const bf16x8*)&Gw[((size_t)t * F + r8a) * (size_t)N + k0 + c8a];
            gv1 = *(const bf16x8*)&Gw[((size_t)t * F + r8b) * (size_t)N + k0 + c8b];
        }

        // Sᵀ = relu(K·Qᵀ): D[m=key][n=q]; kfrag shared across both q-groups
#pragma unroll
        for (int nt = 0; nt < 4; ++nt) {
            bf16x8 k0f = *(const bf16x8*)&Kt[(nt * 16 + l16) * KS + quad * 8];
            bf16x8 k1f = *(const bf16x8*)&Kt[(nt * 16 + l16) * KS + 32 + quad * 8];
#pragma unroll
            for (int qg = 0; qg < 2; ++qg) {
                f32x4 s = (f32x4){0.f, 0.f, 0.f, 0.f};
                s = __builtin_amdgcn_mfma_f32_16x16x32_bf16(k0f, qf[qg][0], s, 0, 0, 0);
                s = __builtin_amdgcn_mfma_f32_16x16x32_bf16(k1f, qf[qg][1], s, 0, 0, 0);
                // D: col=q_local=l16, row=key=nt*16+quad*4+r -> 4 consecutive
                // keys at fixed q -> single b64 store into Sb[q][key]
                bf16x4 sp;
#pragma unroll
                for (int r = 0; r < 4; ++r) sp[r] = (__bf16)fmaxf(s[r], 0.f);
                *(bf16x4*)&Sb[(wave * 32 + qg * 16 + l16) * KS + nt * 16 + quad * 4] = sp;
            }
        }

        // PV: Oᵀ[f][q] — wave reads only its own 32 Sb rows (no barrier)
        bf16x8 sf[2][2];
#pragma unroll
        for (int qg = 0; qg < 2; ++qg) {
            const __bf16* srow = &Sb[(wave * 32 + qg * 16 + l16) * KS];
            sf[qg][0] = *(const bf16x8*)&srow[quad * 8];
            sf[qg][1] = *(const bf16x8*)&srow[32 + quad * 8];
        }
#pragma unroll
        for (int ft = 0; ft < 4; ++ft) {
            bf16x8 g0 = *(const bf16x8*)&Gt[(ft * 16 + l16) * KS + quad * 8];
            bf16x8 g1 = *(const bf16x8*)&Gt[(ft * 16 + l16) * KS + 32 + quad * 8];
#pragma unroll
            for (int qg = 0; qg < 2; ++qg) {
                oacc[ft][qg] = __builtin_amdgcn_mfma_f32_16x16x32_bf16(g0, sf[qg][0], oacc[ft][qg], 0, 0, 0);
                oacc[ft][qg] = __builtin_amdgcn_mfma_f32_16x16x32_bf16(g1, sf[qg][1], oacc[ft][qg], 0, 0, 0);
            }
        }
    }

    // Epilogue: D row = f = ft*16+quad*4+r, col = q = q0+wave*32+qg*16+l16
#pragma unroll
    for (int ft = 0; ft < 4; ++ft)
#pragma unroll
        for (int qg = 0; qg < 2; ++qg)
#pragma unroll
            for (int r = 0; r < 4; ++r) {
                int f = ft * 16 + quad * 4 + r;
                int q = q0 + wave * 32 + qg * 16 + l16;
                unsafeAtomicAdd(&out[((size_t)t * F + f) * (size_t)N + q], oacc[ft][qg][r]);
            }
}

// ---------------------------------------------------------------------------
extern "C" void kernel_launch(void* const* d_in, const int* in_sizes, int n_in,
                              void* d_out, int out_size, void* d_ws, size_t ws_size,
                              hipStream_t stream) {
    const float* x1 = (const float*)d_in[0];
    const float* x2 = (const float*)d_in[1];
    const float* W1 = (const float*)d_in[2];
    const float* b1 = (const float*)d_in[3];
    const float* W2 = (const float*)d_in[4];
    const float* b2 = (const float*)d_in[5];
    const float* W3 = (const float*)d_in[6];
    const float* b3 = (const float*)d_in[7];
    float* out = (float*)d_out;

    __bf16* Qb = (__bf16*)d_ws;
    __bf16* Kb = Qb + (size_t)T * N * F;
    __bf16* Gw = Kb + (size_t)T * N * F;
    __bf16* Wb = Gw + (size_t)T * N * F;

    prep_w_kernel<<<dim3(3 * F * C / 256), dim3(256), 0, stream>>>(W1, W2, W3, Wb);
    proj_kernel<<<dim3(T * (N / 64)), dim3(256), 0, stream>>>(
        x1, x2, Wb, b1, b2, b3, Qb, Kb, Gw);
    zero_out_kernel<<<dim3(T * F * N / 4 / 256), dim3(256), 0, stream>>>(out);
    attn_kernel<<<dim3(T * 32 * KSPLIT), dim3(256), 0, stream>>>(Qb, Kb, Gw, out);
}